// Round 15
// baseline (36.395 us; speedup 1.0000x reference)
//
#include <hip/hip_runtime.h>
#include <math.h>

// Problem: stimulus (32, 128*256) f32; H_real/H_imag (512, 256, 3) f32; out (32, 512) f32.
//   qf = fft2(q) over (128, 256); per (b,m): r = m%128;
//   acc = sum_w sum_d |ifft256(qf[b,r,:] * H[m,:,w])| ; out = acc/(256*256*3), thr 0.3.
//
// Structure (round 15 = round 14 + h=8 exchange on DPP row_ror:8):
//  k_cols: pair-packed 128-pt column FFTs (z = col_d + i*col_{d+128}, Hermitian unpack),
//    natural-in DIF (rows land at slot brev7(f)); yc stored as packed fp16 (4 MB).
//    Ht pre-pass: one block per m, LDS-staged, coalesced both sides, fp16 (1.5 MB).
//  k_recon: cooperative fwd 256-pt row FFT (4 waves, each owns quarter j=wid) +
//    per-wave 3-wavelength inverse-DIT iFFT for m = r + 128*wid; pointwise in bitrev
//    k-space. Exchange plan: h=1,2 DPP quad_perm; h=4 __shfl_xor; h=8 DPP row_ror:8
//    (lane^8 == ror8 within 16-row; VALU pipe, verified correct in round 10);
//    h=16,32 permlane16/32_swap. Twiddles from ONE sincos via squaring chain.
//    Complex = ext_vector float2 -> v_pk_* packed fp32.

#define TWO_PI 6.28318530717958647692f
#define PI_F   3.14159265358979323846f

#if __has_builtin(__builtin_amdgcn_permlane16_swap)
#define USE_PL16 1
#else
#define USE_PL16 0
#endif
#if __has_builtin(__builtin_amdgcn_permlane32_swap)
#define USE_PL32 1
#else
#define USE_PL32 0
#endif

typedef float f2 __attribute__((ext_vector_type(2)));
typedef _Float16 h2v __attribute__((ext_vector_type(2)));
typedef unsigned int uint2v __attribute__((ext_vector_type(2)));

__device__ inline f2 mkf2(float x, float y) { f2 r; r[0] = x; r[1] = y; return r; }
__device__ inline f2 conjf2(f2 a) { return mkf2(a[0], -a[1]); }
__device__ inline h2v f2h(f2 v) { h2v h; h[0] = (_Float16)v[0]; h[1] = (_Float16)v[1]; return h; }
__device__ inline f2 h2f(h2v h) { f2 r; r[0] = (float)h[0]; r[1] = (float)h[1]; return r; }

__device__ inline f2 cmul(f2 a, f2 b) {
    const f2 axx = __builtin_shufflevector(a, a, 0, 0);
    const f2 ayn = mkf2(-a[1], a[1]);
    const f2 byx = __builtin_shufflevector(b, b, 1, 0);
    return axx * b + ayn * byx;
}
__device__ inline f2 csq(f2 a) { return cmul(a, a); }
// v' = A*v + B*o  (4 packed fma)
__device__ inline f2 ab2(f2 A, f2 v, f2 B, f2 o) {
    const f2 Axx = __builtin_shufflevector(A, A, 0, 0);
    const f2 Ayn = mkf2(-A[1], A[1]);
    const f2 Bxx = __builtin_shufflevector(B, B, 0, 0);
    const f2 Byn = mkf2(-B[1], B[1]);
    const f2 vyx = __builtin_shufflevector(v, v, 1, 0);
    const f2 oyx = __builtin_shufflevector(o, o, 1, 0);
    return Axx * v + Ayn * vyx + Bxx * o + Byn * oyx;
}
// a + S*b  (2 packed fma)
__device__ inline f2 cfma2(f2 S, f2 b, f2 a) {
    const f2 Sxx = __builtin_shufflevector(S, S, 0, 0);
    const f2 Syn = mkf2(-S[1], S[1]);
    const f2 byx = __builtin_shufflevector(b, b, 1, 0);
    return Sxx * b + (Syn * byx + a);
}
__device__ inline f2 shfl_xor_c(f2 v, int mask) {
    return mkf2(__shfl_xor(v[0], mask, 64), __shfl_xor(v[1], mask, 64));
}

#define DPP_XOR1 0xB1   // quad_perm [1,0,3,2]
#define DPP_XOR2 0x4E   // quad_perm [2,3,0,1]
#define DPP_ROR8 0x128  // row_ror:8 == lane^8 within each 16-lane row
template <int CTRL>
__device__ inline f2 dpp_quad(f2 v) {
    return mkf2(
        __int_as_float(__builtin_amdgcn_update_dpp(__float_as_int(v[0]), __float_as_int(v[0]),
                                                   CTRL, 0xF, 0xF, false)),
        __int_as_float(__builtin_amdgcn_update_dpp(__float_as_int(v[1]), __float_as_int(v[1]),
                                                   CTRL, 0xF, 0xF, false)));
}

#if USE_PL16
__device__ inline void swap16c(f2 v, f2& a, f2& b) {
    uint2v rx = __builtin_amdgcn_permlane16_swap(__float_as_uint(v[0]), __float_as_uint(v[0]), false, false);
    uint2v ry = __builtin_amdgcn_permlane16_swap(__float_as_uint(v[1]), __float_as_uint(v[1]), false, false);
    a = mkf2(__uint_as_float(rx[0]), __uint_as_float(ry[0]));
    b = mkf2(__uint_as_float(rx[1]), __uint_as_float(ry[1]));
}
#endif
#if USE_PL32
__device__ inline void swap32c(f2 v, f2& a, f2& b) {
    uint2v rx = __builtin_amdgcn_permlane32_swap(__float_as_uint(v[0]), __float_as_uint(v[0]), false, false);
    uint2v ry = __builtin_amdgcn_permlane32_swap(__float_as_uint(v[1]), __float_as_uint(v[1]), false, false);
    a = mkf2(__uint_as_float(rx[0]), __uint_as_float(ry[0]));
    b = mkf2(__uint_as_float(rx[1]), __uint_as_float(ry[1]));
}
#endif

// ---------------- Pass 1 (fused): pair-packed col FFT (fp16 out) + Ht (fp16) -----
__global__ __launch_bounds__(256) void k_cols(const float* __restrict__ x,
                                              h2v* __restrict__ yh,
                                              const float* __restrict__ Hr,
                                              const float* __restrict__ Hi,
                                              h2v* __restrict__ Hth) {
    const int tid = threadIdx.x;

    if (blockIdx.x >= 256) {
        const int m = blockIdx.x - 256;           // 0..511
        __shared__ h2v hl[768];
        const float* hr = Hr + (size_t)m * 768;
        const float* hi = Hi + (size_t)m * 768;
#pragma unroll
        for (int i = tid; i < 768; i += 256) {    // i = k*3 + w, coalesced reads
            hl[i] = f2h(mkf2(hr[i], hi[i]));
        }
        __syncthreads();
        h2v* ho = Hth + (size_t)m * 768;
#pragma unroll
        for (int o = tid; o < 768; o += 256) {    // coalesced writes
            const int w = o >> 8;
            const int p = o & 255;
            const int k = __brev((unsigned)p) >> 24;
            ho[o] = hl[k * 3 + w];                 // gather in LDS
        }
        return;
    }

    __shared__ f2 sm[128][17];
    __shared__ f2 tw[64];

    if (tid < 64) {
        float sn, cs;
        __sincosf(-TWO_PI * (float)tid * (1.0f / 128.0f), &sn, &cs);
        tw[tid] = mkf2(cs, sn);
    }

    const int b  = blockIdx.x >> 3;
    const int d0 = (blockIdx.x & 7) << 4;   // 0,16,...,112
    const int c  = tid & 15;                 // packed column within block
    const int r0 = tid >> 4;                 // 0..15
    const int d  = d0 + c;                   // real column pair (d, d+128)
    const size_t xb = (size_t)b * 32768;

    // natural-r load, pack two real columns into one complex sequence
#pragma unroll
    for (int r = r0; r < 128; r += 16) {
        sm[r][c] = mkf2(x[xb + (size_t)r * 256 + d],
                        x[xb + (size_t)r * 256 + d + 128]);
    }
    __syncthreads();

    // 7 DIF stages (h = 64 >> st): (a,b) -> (a+b, (a-b)*W), W = tw[(i&(h-1)) << st]
#pragma unroll
    for (int st = 0; st < 7; ++st) {
        const int h = 64 >> st;
#pragma unroll
        for (int k = 0; k < 4; ++k) {  // 64 butterflies x 16 cols / 256 threads
            const int idx = tid + (k << 8);
            const int cc  = idx & 15;
            const int j   = idx >> 4;  // 0..63
            const int pos = j & (h - 1);
            const int i0  = (j << 1) - pos;
            const int i1  = i0 + h;
            const f2 w  = tw[pos << st];
            const f2 a  = sm[i0][cc];
            const f2 bv = sm[i1][cc];
            sm[i0][cc] = a + bv;
            sm[i1][cc] = cmul(a - bv, w);
        }
        __syncthreads();
    }

    // Hermitian unpack + fp16 store. Slot s holds freq f=brev7(s); partner freq 128-f
    // at slot brev7((128-f)&127). Yd = (Z+conj(Zp))/2; Y_{d+128} = -i*(Z-conj(Zp))/2.
#pragma unroll
    for (int s = r0; s < 128; s += 16) {
        const int f  = __brev((unsigned)s) >> 25;
        const int pf = (128 - f) & 127;
        const int ps = __brev((unsigned)pf) >> 25;
        const f2 Zf = sm[s][c];
        const f2 Zp = sm[ps][c];
        const f2 sum = mkf2((Zf[0] + Zp[0]) * 0.5f, (Zf[1] - Zp[1]) * 0.5f);
        const f2 dif = mkf2((Zf[0] - Zp[0]) * 0.5f, (Zf[1] + Zp[1]) * 0.5f);
        const f2 Yb  = mkf2(dif[1], -dif[0]);   // -i * dif
        const size_t row = ((size_t)b * 128 + s) * 256;
        yh[row + d]       = f2h(sum);
        yh[row + d + 128] = f2h(Yb);
    }
}

// ---------------- Pass 2 (fused): cooperative fwd row FFT + 4x3 iFFT -------------
// grid = 4096 blocks (b,r), 256 threads (4 waves). wave wid handles m = r + 128*wid.
// yh rows are stored at slot brev7(r) (k_cols DIF output order); yh/Hth are fp16.
__global__ __launch_bounds__(256) void k_recon(const h2v* __restrict__ yh,
                                               const h2v* __restrict__ Hth,
                                               float* __restrict__ out) {
    __shared__ f2 sh[256];
    const int lane = threadIdx.x & 63;
    const int wid  = threadIdx.x >> 6;
    const int b    = blockIdx.x >> 7;
    const int r    = blockIdx.x & 127;
    const int m    = r + (wid << 7);
    const int rs   = __brev((unsigned)r) >> 25;   // storage slot of freq-row r

    float sn, cs;
    // beta = exp(+i pi lane/128); squaring chain gives all inverse-DIT constants.
    __sincosf(PI_F * (float)lane * (1.0f / 128.0f), &sn, &cs);
    const f2 wi0 = mkf2(cs, sn);   // beta    (h=128 twiddle)
    const f2 w64 = csq(wi0);       // beta^2  (h=64)
    const f2 S32 = csq(w64);       // beta^4  -> h=32 swap, no select
    const f2 S16 = csq(S32);       // beta^8  -> h=16 swap, no select
    const f2 b16 = csq(S16);       // beta^16 (h=8)
    const f2 b32 = csq(b16);       // beta^32 (h=4)
    const f2 b64 = csq(b32);       // beta^64 (h=2)
    const f2 one = mkf2(1.0f, 0.0f);
    const f2 A8 = (lane & 8) ? b16 : one, B8 = (lane & 8) ? one : b16;
    const f2 A4 = (lane & 4) ? b32 : one, B4 = (lane & 4) ? one : b32;
    const f2 A2 = (lane & 2) ? b64 : one, B2 = (lane & 2) ? one : b64;
    const f2 sg1 = (lane & 1) ? mkf2(-1.0f, -1.0f) : mkf2(1.0f, 1.0f);
    const f2 wi1 = mkf2(-wi0[1], wi0[0]);
#if !USE_PL16
    const f2 A16 = (lane & 16) ? S16 : one, B16 = (lane & 16) ? one : S16;
#endif
#if !USE_PL32
    const f2 A32 = (lane & 32) ? S32 : one, B32 = (lane & 32) ? one : S32;
#endif

    // ---- forward row FFT: all 4 waves cooperate; wave wid owns quarter j=wid ----
    {
        const f2 gam    = conjf2(wi0);
        const f2 w128_0 = gam;
        const f2 w128_1 = mkf2(gam[1], -gam[0]);
        const f2 w64f = conjf2(w64);
        const f2 g4   = conjf2(S32);
        const f2 g8   = conjf2(S16);
        const f2 g16  = conjf2(b16);
        const f2 g32  = conjf2(b32);
        const f2 g64  = conjf2(b64);
#if USE_PL32
        const f2 P32 = (lane & 32) ? mkf2(-g4[0], -g4[1]) : one;
        const f2 Q32 = (lane & 32) ? g4 : one;
#else
        const f2 A32f = (lane & 32) ? g4 : one;
        const f2 B32f = (lane & 32) ? mkf2(-g4[0], -g4[1]) : one;
#endif
#if USE_PL16
        const f2 P16 = (lane & 16) ? mkf2(-g8[0], -g8[1]) : one;
        const f2 Q16 = (lane & 16) ? g8 : one;
#else
        const f2 A16f = (lane & 16) ? g8 : one;
        const f2 B16f = (lane & 16) ? mkf2(-g8[0], -g8[1]) : one;
#endif
        const f2 A8f = (lane & 8) ? g16 : one;
        const f2 B8f = (lane & 8) ? mkf2(-g16[0], -g16[1]) : one;
        const f2 A4f = (lane & 4) ? g32 : one;
        const f2 B4f = (lane & 4) ? mkf2(-g32[0], -g32[1]) : one;
        const f2 A2f = (lane & 2) ? g64 : one;
        const f2 B2f = (lane & 2) ? mkf2(-g64[0], -g64[1]) : one;

        const h2v* xr = yh + ((size_t)(b * 128 + rs)) * 256;
        f2 v0 = h2f(xr[lane]);
        f2 v1 = h2f(xr[64 + lane]);
        f2 v2 = h2f(xr[128 + lane]);
        f2 v3 = h2f(xr[192 + lane]);

        // in-register DIF h=128, h=64 (all 4 quarters; cheap, redundant per wave)
        { f2 a = v0; v0 = a + v2; v2 = cmul(a - v2, w128_0); }
        { f2 a = v1; v1 = a + v3; v3 = cmul(a - v3, w128_1); }
        { f2 a = v0; v0 = a + v1; v1 = cmul(a - v1, w64f); }
        { f2 a = v2; v2 = a + v3; v3 = cmul(a - v3, w64f); }

        // own quarter (wid is wave-uniform -> scalar selects, no dyn reg indexing)
        f2 u = (wid == 0) ? v0 : (wid == 1) ? v1 : (wid == 2) ? v2 : v3;

        // 6 cross-lane DIF stages on u only
        {
#if USE_PL32
            f2 a, bb; swap32c(u, a, bb);
            u = ab2(P32, a, Q32, bb);
#else
            const f2 o = shfl_xor_c(u, 32);
            u = ab2(A32f, u, B32f, o);
#endif
        }
        {
#if USE_PL16
            f2 a, bb; swap16c(u, a, bb);
            u = ab2(P16, a, Q16, bb);
#else
            const f2 o = shfl_xor_c(u, 16);
            u = ab2(A16f, u, B16f, o);
#endif
        }
        { const f2 o = dpp_quad<DPP_ROR8>(u); u = ab2(A8f, u, B8f, o); }   // h=8 DPP
        { const f2 o = shfl_xor_c(u, 4); u = ab2(A4f, u, B4f, o); }
        { const f2 o = dpp_quad<DPP_XOR2>(u); u = ab2(A2f, u, B2f, o); }
        { const f2 o = dpp_quad<DPP_XOR1>(u); u = sg1 * u + o; }

        sh[(wid << 6) + lane] = u;
    }
    __syncthreads();

    f2 qv[4];
#pragma unroll
    for (int j = 0; j < 4; ++j) qv[j] = sh[j * 64 + lane];

    const h2v* hp = Hth + (size_t)m * 768;
    f2 v[3][4];
#pragma unroll
    for (int w = 0; w < 3; ++w)
#pragma unroll
        for (int j = 0; j < 4; ++j)
            v[w][j] = cmul(qv[j], h2f(hp[w * 256 + j * 64 + lane]));

    // h=1 (DPP, W==1): v' = sgn*v + o
#pragma unroll
    for (int w = 0; w < 3; ++w)
#pragma unroll
        for (int j = 0; j < 4; ++j) {
            const f2 o = dpp_quad<DPP_XOR1>(v[w][j]);
            v[w][j] = sg1 * v[w][j] + o;
        }
    // h=2 (DPP)
#pragma unroll
    for (int w = 0; w < 3; ++w)
#pragma unroll
        for (int j = 0; j < 4; ++j) {
            const f2 o = dpp_quad<DPP_XOR2>(v[w][j]);
            v[w][j] = ab2(A2, v[w][j], B2, o);
        }
    // h=4 (shfl)
#pragma unroll
    for (int w = 0; w < 3; ++w)
#pragma unroll
        for (int j = 0; j < 4; ++j) {
            const f2 o = shfl_xor_c(v[w][j], 4);
            v[w][j] = ab2(A4, v[w][j], B4, o);
        }
    // h=8 (DPP row_ror:8 -- VALU pipe, replaces shfl)
#pragma unroll
    for (int w = 0; w < 3; ++w)
#pragma unroll
        for (int j = 0; j < 4; ++j) {
            const f2 o = dpp_quad<DPP_ROR8>(v[w][j]);
            v[w][j] = ab2(A8, v[w][j], B8, o);
        }
    // h=16 (swap): v' = a + S16*b
#pragma unroll
    for (int w = 0; w < 3; ++w)
#pragma unroll
        for (int j = 0; j < 4; ++j) {
#if USE_PL16
            f2 a, bb; swap16c(v[w][j], a, bb);
            v[w][j] = cfma2(S16, bb, a);
#else
            const f2 o = shfl_xor_c(v[w][j], 16);
            v[w][j] = ab2(A16, v[w][j], B16, o);
#endif
        }
    // h=32 (swap): v' = a + S32*b
#pragma unroll
    for (int w = 0; w < 3; ++w)
#pragma unroll
        for (int j = 0; j < 4; ++j) {
#if USE_PL32
            f2 a, bb; swap32c(v[w][j], a, bb);
            v[w][j] = cfma2(S32, bb, a);
#else
            const f2 o = shfl_xor_c(v[w][j], 32);
            v[w][j] = ab2(A32, v[w][j], B32, o);
#endif
        }
    // in-register h=64, h=128
#pragma unroll
    for (int w = 0; w < 3; ++w) {
        f2 tv = cmul(w64, v[w][1]);
        f2 a = v[w][0];
        v[w][0] = a + tv; v[w][1] = a - tv;
        tv = cmul(w64, v[w][3]);
        a = v[w][2];
        v[w][2] = a + tv; v[w][3] = a - tv;
        tv = cmul(wi0, v[w][2]);
        a = v[w][0];
        v[w][0] = a + tv; v[w][2] = a - tv;
        tv = cmul(wi1, v[w][3]);
        a = v[w][1];
        v[w][1] = a + tv; v[w][3] = a - tv;
    }

    float acc = 0.0f;
#pragma unroll
    for (int w = 0; w < 3; ++w)
#pragma unroll
        for (int j = 0; j < 4; ++j) {
            const f2 sq = v[w][j] * v[w][j];
            acc += __builtin_amdgcn_sqrtf(sq[0] + sq[1]);
        }

#pragma unroll
    for (int off = 32; off > 0; off >>= 1) acc += __shfl_xor(acc, off, 64);

    if (lane == 0) {
        const float focused = acc * (1.0f / (256.0f * 256.0f * 3.0f));
        out[b * 512 + m] = (focused > 0.3f) ? focused : 0.0f;
    }
}

extern "C" void kernel_launch(void* const* d_in, const int* in_sizes, int n_in,
                              void* d_out, int out_size, void* d_ws, size_t ws_size,
                              hipStream_t stream) {
    (void)in_sizes; (void)n_in; (void)out_size; (void)ws_size;
    const float* stim = (const float*)d_in[0];   // (32, 32768)
    const float* Hr   = (const float*)d_in[1];   // (512, 256, 3)
    const float* Hi   = (const float*)d_in[2];   // (512, 256, 3)
    float* out = (float*)d_out;                  // (32, 512)

    h2v* yh  = (h2v*)d_ws;                                                 // 4 MB (fp16)
    h2v* Hth = (h2v*)((char*)d_ws + (size_t)32 * 128 * 256 * sizeof(h2v)); // 1.5 MB (fp16)

    k_cols<<<256 + 512, 256, 0, stream>>>(stim, yh, Hr, Hi, Hth);
    k_recon<<<4096, 256, 0, stream>>>(yh, Hth, out);
}

// Round 16
// 35.268 us; speedup vs baseline: 1.0320x; 1.0320x over previous
//
#include <hip/hip_runtime.h>
#include <math.h>

// Problem: stimulus (32, 128*256) f32; H_real/H_imag (512, 256, 3) f32; out (32, 512) f32.
//   qf = fft2(q) over (128, 256); per (b,m): r = m%128;
//   acc = sum_w sum_d |ifft256(qf[b,r,:] * H[m,:,w])| ; out = acc/(256*256*3), thr 0.3.
//
// FINAL STRUCTURE (= round 14, the measured optimum; round-15 A/B showed h=8-on-DPP
// regresses -2.6% -- the h=8 shfl overlaps on the LDS pipe with other waves' VALU):
//  k_cols: pair-packed 128-pt column FFTs (z = col_d + i*col_{d+128}, Hermitian unpack),
//    natural-in DIF (rows land at slot brev7(f)); yc stored as packed fp16 (4 MB).
//    Ht pre-pass: one block per m, LDS-staged, coalesced both sides, fp16 (1.5 MB).
//  k_recon: cooperative fwd 256-pt row FFT (4 waves, each owns quarter j=wid) +
//    per-wave 3-wavelength inverse-DIT iFFT for m = r + 128*wid; pointwise in bitrev
//    k-space. Exchange plan: h=1,2 DPP quad_perm; h=4,8 __shfl_xor;
//    h=16,32 permlane16/32_swap. Twiddles from ONE sincos via squaring chain.
//    Complex = ext_vector float2 -> v_pk_* packed fp32.

#define TWO_PI 6.28318530717958647692f
#define PI_F   3.14159265358979323846f

#if __has_builtin(__builtin_amdgcn_permlane16_swap)
#define USE_PL16 1
#else
#define USE_PL16 0
#endif
#if __has_builtin(__builtin_amdgcn_permlane32_swap)
#define USE_PL32 1
#else
#define USE_PL32 0
#endif

typedef float f2 __attribute__((ext_vector_type(2)));
typedef _Float16 h2v __attribute__((ext_vector_type(2)));
typedef unsigned int uint2v __attribute__((ext_vector_type(2)));

__device__ inline f2 mkf2(float x, float y) { f2 r; r[0] = x; r[1] = y; return r; }
__device__ inline f2 conjf2(f2 a) { return mkf2(a[0], -a[1]); }
__device__ inline h2v f2h(f2 v) { h2v h; h[0] = (_Float16)v[0]; h[1] = (_Float16)v[1]; return h; }
__device__ inline f2 h2f(h2v h) { f2 r; r[0] = (float)h[0]; r[1] = (float)h[1]; return r; }

__device__ inline f2 cmul(f2 a, f2 b) {
    const f2 axx = __builtin_shufflevector(a, a, 0, 0);
    const f2 ayn = mkf2(-a[1], a[1]);
    const f2 byx = __builtin_shufflevector(b, b, 1, 0);
    return axx * b + ayn * byx;
}
__device__ inline f2 csq(f2 a) { return cmul(a, a); }
// v' = A*v + B*o  (4 packed fma)
__device__ inline f2 ab2(f2 A, f2 v, f2 B, f2 o) {
    const f2 Axx = __builtin_shufflevector(A, A, 0, 0);
    const f2 Ayn = mkf2(-A[1], A[1]);
    const f2 Bxx = __builtin_shufflevector(B, B, 0, 0);
    const f2 Byn = mkf2(-B[1], B[1]);
    const f2 vyx = __builtin_shufflevector(v, v, 1, 0);
    const f2 oyx = __builtin_shufflevector(o, o, 1, 0);
    return Axx * v + Ayn * vyx + Bxx * o + Byn * oyx;
}
// a + S*b  (2 packed fma)
__device__ inline f2 cfma2(f2 S, f2 b, f2 a) {
    const f2 Sxx = __builtin_shufflevector(S, S, 0, 0);
    const f2 Syn = mkf2(-S[1], S[1]);
    const f2 byx = __builtin_shufflevector(b, b, 1, 0);
    return Sxx * b + (Syn * byx + a);
}
__device__ inline f2 shfl_xor_c(f2 v, int mask) {
    return mkf2(__shfl_xor(v[0], mask, 64), __shfl_xor(v[1], mask, 64));
}

#define DPP_XOR1 0xB1  // quad_perm [1,0,3,2]
#define DPP_XOR2 0x4E  // quad_perm [2,3,0,1]
template <int CTRL>
__device__ inline f2 dpp_quad(f2 v) {
    return mkf2(
        __int_as_float(__builtin_amdgcn_update_dpp(__float_as_int(v[0]), __float_as_int(v[0]),
                                                   CTRL, 0xF, 0xF, false)),
        __int_as_float(__builtin_amdgcn_update_dpp(__float_as_int(v[1]), __float_as_int(v[1]),
                                                   CTRL, 0xF, 0xF, false)));
}

#if USE_PL16
__device__ inline void swap16c(f2 v, f2& a, f2& b) {
    uint2v rx = __builtin_amdgcn_permlane16_swap(__float_as_uint(v[0]), __float_as_uint(v[0]), false, false);
    uint2v ry = __builtin_amdgcn_permlane16_swap(__float_as_uint(v[1]), __float_as_uint(v[1]), false, false);
    a = mkf2(__uint_as_float(rx[0]), __uint_as_float(ry[0]));
    b = mkf2(__uint_as_float(rx[1]), __uint_as_float(ry[1]));
}
#endif
#if USE_PL32
__device__ inline void swap32c(f2 v, f2& a, f2& b) {
    uint2v rx = __builtin_amdgcn_permlane32_swap(__float_as_uint(v[0]), __float_as_uint(v[0]), false, false);
    uint2v ry = __builtin_amdgcn_permlane32_swap(__float_as_uint(v[1]), __float_as_uint(v[1]), false, false);
    a = mkf2(__uint_as_float(rx[0]), __uint_as_float(ry[0]));
    b = mkf2(__uint_as_float(rx[1]), __uint_as_float(ry[1]));
}
#endif

// ---------------- Pass 1 (fused): pair-packed col FFT (fp16 out) + Ht (fp16) -----
// blocks [0,256): block = (b, 16 packed column-pairs (d, d+128)). Natural-in DIF in
// LDS (7 stages), bitrev-out over r; Hermitian unpack, fp16 store.
// blocks [256,768): one block per m: LDS-staged Ht[m][w][p] = fp16((Hr+i*Hi)[m][brev8(p)][w]).
__global__ __launch_bounds__(256) void k_cols(const float* __restrict__ x,
                                              h2v* __restrict__ yh,
                                              const float* __restrict__ Hr,
                                              const float* __restrict__ Hi,
                                              h2v* __restrict__ Hth) {
    const int tid = threadIdx.x;

    if (blockIdx.x >= 256) {
        const int m = blockIdx.x - 256;           // 0..511
        __shared__ h2v hl[768];
        const float* hr = Hr + (size_t)m * 768;
        const float* hi = Hi + (size_t)m * 768;
#pragma unroll
        for (int i = tid; i < 768; i += 256) {    // i = k*3 + w, coalesced reads
            hl[i] = f2h(mkf2(hr[i], hi[i]));
        }
        __syncthreads();
        h2v* ho = Hth + (size_t)m * 768;
#pragma unroll
        for (int o = tid; o < 768; o += 256) {    // coalesced writes
            const int w = o >> 8;
            const int p = o & 255;
            const int k = __brev((unsigned)p) >> 24;
            ho[o] = hl[k * 3 + w];                 // gather in LDS
        }
        return;
    }

    __shared__ f2 sm[128][17];
    __shared__ f2 tw[64];

    if (tid < 64) {
        float sn, cs;
        __sincosf(-TWO_PI * (float)tid * (1.0f / 128.0f), &sn, &cs);
        tw[tid] = mkf2(cs, sn);
    }

    const int b  = blockIdx.x >> 3;
    const int d0 = (blockIdx.x & 7) << 4;   // 0,16,...,112
    const int c  = tid & 15;                 // packed column within block
    const int r0 = tid >> 4;                 // 0..15
    const int d  = d0 + c;                   // real column pair (d, d+128)
    const size_t xb = (size_t)b * 32768;

    // natural-r load, pack two real columns into one complex sequence
#pragma unroll
    for (int r = r0; r < 128; r += 16) {
        sm[r][c] = mkf2(x[xb + (size_t)r * 256 + d],
                        x[xb + (size_t)r * 256 + d + 128]);
    }
    __syncthreads();

    // 7 DIF stages (h = 64 >> st): (a,b) -> (a+b, (a-b)*W), W = tw[(i&(h-1)) << st]
#pragma unroll
    for (int st = 0; st < 7; ++st) {
        const int h = 64 >> st;
#pragma unroll
        for (int k = 0; k < 4; ++k) {  // 64 butterflies x 16 cols / 256 threads
            const int idx = tid + (k << 8);
            const int cc  = idx & 15;
            const int j   = idx >> 4;  // 0..63
            const int pos = j & (h - 1);
            const int i0  = (j << 1) - pos;
            const int i1  = i0 + h;
            const f2 w  = tw[pos << st];
            const f2 a  = sm[i0][cc];
            const f2 bv = sm[i1][cc];
            sm[i0][cc] = a + bv;
            sm[i1][cc] = cmul(a - bv, w);
        }
        __syncthreads();
    }

    // Hermitian unpack + fp16 store. Slot s holds freq f=brev7(s); partner freq 128-f
    // at slot brev7((128-f)&127). Yd = (Z+conj(Zp))/2; Y_{d+128} = -i*(Z-conj(Zp))/2.
#pragma unroll
    for (int s = r0; s < 128; s += 16) {
        const int f  = __brev((unsigned)s) >> 25;
        const int pf = (128 - f) & 127;
        const int ps = __brev((unsigned)pf) >> 25;
        const f2 Zf = sm[s][c];
        const f2 Zp = sm[ps][c];
        const f2 sum = mkf2((Zf[0] + Zp[0]) * 0.5f, (Zf[1] - Zp[1]) * 0.5f);
        const f2 dif = mkf2((Zf[0] - Zp[0]) * 0.5f, (Zf[1] + Zp[1]) * 0.5f);
        const f2 Yb  = mkf2(dif[1], -dif[0]);   // -i * dif
        const size_t row = ((size_t)b * 128 + s) * 256;
        yh[row + d]       = f2h(sum);
        yh[row + d + 128] = f2h(Yb);
    }
}

// ---------------- Pass 2 (fused): cooperative fwd row FFT + 4x3 iFFT -------------
// grid = 4096 blocks (b,r), 256 threads (4 waves). wave wid handles m = r + 128*wid.
// yh rows are stored at slot brev7(r) (k_cols DIF output order); yh/Hth are fp16.
__global__ __launch_bounds__(256) void k_recon(const h2v* __restrict__ yh,
                                               const h2v* __restrict__ Hth,
                                               float* __restrict__ out) {
    __shared__ f2 sh[256];
    const int lane = threadIdx.x & 63;
    const int wid  = threadIdx.x >> 6;
    const int b    = blockIdx.x >> 7;
    const int r    = blockIdx.x & 127;
    const int m    = r + (wid << 7);
    const int rs   = __brev((unsigned)r) >> 25;   // storage slot of freq-row r

    float sn, cs;
    // beta = exp(+i pi lane/128); squaring chain gives all inverse-DIT constants.
    __sincosf(PI_F * (float)lane * (1.0f / 128.0f), &sn, &cs);
    const f2 wi0 = mkf2(cs, sn);   // beta    (h=128 twiddle)
    const f2 w64 = csq(wi0);       // beta^2  (h=64)
    const f2 S32 = csq(w64);       // beta^4  -> h=32 swap, no select
    const f2 S16 = csq(S32);       // beta^8  -> h=16 swap, no select
    const f2 b16 = csq(S16);       // beta^16 (h=8)
    const f2 b32 = csq(b16);       // beta^32 (h=4)
    const f2 b64 = csq(b32);       // beta^64 (h=2)
    const f2 one = mkf2(1.0f, 0.0f);
    const f2 A8 = (lane & 8) ? b16 : one, B8 = (lane & 8) ? one : b16;
    const f2 A4 = (lane & 4) ? b32 : one, B4 = (lane & 4) ? one : b32;
    const f2 A2 = (lane & 2) ? b64 : one, B2 = (lane & 2) ? one : b64;
    const f2 sg1 = (lane & 1) ? mkf2(-1.0f, -1.0f) : mkf2(1.0f, 1.0f);
    const f2 wi1 = mkf2(-wi0[1], wi0[0]);
#if !USE_PL16
    const f2 A16 = (lane & 16) ? S16 : one, B16 = (lane & 16) ? one : S16;
#endif
#if !USE_PL32
    const f2 A32 = (lane & 32) ? S32 : one, B32 = (lane & 32) ? one : S32;
#endif

    // ---- forward row FFT: all 4 waves cooperate; wave wid owns quarter j=wid ----
    {
        const f2 gam    = conjf2(wi0);
        const f2 w128_0 = gam;
        const f2 w128_1 = mkf2(gam[1], -gam[0]);
        const f2 w64f = conjf2(w64);
        const f2 g4   = conjf2(S32);
        const f2 g8   = conjf2(S16);
        const f2 g16  = conjf2(b16);
        const f2 g32  = conjf2(b32);
        const f2 g64  = conjf2(b64);
#if USE_PL32
        const f2 P32 = (lane & 32) ? mkf2(-g4[0], -g4[1]) : one;
        const f2 Q32 = (lane & 32) ? g4 : one;
#else
        const f2 A32f = (lane & 32) ? g4 : one;
        const f2 B32f = (lane & 32) ? mkf2(-g4[0], -g4[1]) : one;
#endif
#if USE_PL16
        const f2 P16 = (lane & 16) ? mkf2(-g8[0], -g8[1]) : one;
        const f2 Q16 = (lane & 16) ? g8 : one;
#else
        const f2 A16f = (lane & 16) ? g8 : one;
        const f2 B16f = (lane & 16) ? mkf2(-g8[0], -g8[1]) : one;
#endif
        const f2 A8f = (lane & 8) ? g16 : one;
        const f2 B8f = (lane & 8) ? mkf2(-g16[0], -g16[1]) : one;
        const f2 A4f = (lane & 4) ? g32 : one;
        const f2 B4f = (lane & 4) ? mkf2(-g32[0], -g32[1]) : one;
        const f2 A2f = (lane & 2) ? g64 : one;
        const f2 B2f = (lane & 2) ? mkf2(-g64[0], -g64[1]) : one;

        const h2v* xr = yh + ((size_t)(b * 128 + rs)) * 256;
        f2 v0 = h2f(xr[lane]);
        f2 v1 = h2f(xr[64 + lane]);
        f2 v2 = h2f(xr[128 + lane]);
        f2 v3 = h2f(xr[192 + lane]);

        // in-register DIF h=128, h=64 (all 4 quarters; cheap, redundant per wave)
        { f2 a = v0; v0 = a + v2; v2 = cmul(a - v2, w128_0); }
        { f2 a = v1; v1 = a + v3; v3 = cmul(a - v3, w128_1); }
        { f2 a = v0; v0 = a + v1; v1 = cmul(a - v1, w64f); }
        { f2 a = v2; v2 = a + v3; v3 = cmul(a - v3, w64f); }

        // own quarter (wid is wave-uniform -> scalar selects, no dyn reg indexing)
        f2 u = (wid == 0) ? v0 : (wid == 1) ? v1 : (wid == 2) ? v2 : v3;

        // 6 cross-lane DIF stages on u only
        {
#if USE_PL32
            f2 a, bb; swap32c(u, a, bb);
            u = ab2(P32, a, Q32, bb);
#else
            const f2 o = shfl_xor_c(u, 32);
            u = ab2(A32f, u, B32f, o);
#endif
        }
        {
#if USE_PL16
            f2 a, bb; swap16c(u, a, bb);
            u = ab2(P16, a, Q16, bb);
#else
            const f2 o = shfl_xor_c(u, 16);
            u = ab2(A16f, u, B16f, o);
#endif
        }
        { const f2 o = shfl_xor_c(u, 8); u = ab2(A8f, u, B8f, o); }
        { const f2 o = shfl_xor_c(u, 4); u = ab2(A4f, u, B4f, o); }
        { const f2 o = dpp_quad<DPP_XOR2>(u); u = ab2(A2f, u, B2f, o); }
        { const f2 o = dpp_quad<DPP_XOR1>(u); u = sg1 * u + o; }

        sh[(wid << 6) + lane] = u;
    }
    __syncthreads();

    f2 qv[4];
#pragma unroll
    for (int j = 0; j < 4; ++j) qv[j] = sh[j * 64 + lane];

    const h2v* hp = Hth + (size_t)m * 768;
    f2 v[3][4];
#pragma unroll
    for (int w = 0; w < 3; ++w)
#pragma unroll
        for (int j = 0; j < 4; ++j)
            v[w][j] = cmul(qv[j], h2f(hp[w * 256 + j * 64 + lane]));

    // h=1 (DPP, W==1): v' = sgn*v + o
#pragma unroll
    for (int w = 0; w < 3; ++w)
#pragma unroll
        for (int j = 0; j < 4; ++j) {
            const f2 o = dpp_quad<DPP_XOR1>(v[w][j]);
            v[w][j] = sg1 * v[w][j] + o;
        }
    // h=2 (DPP)
#pragma unroll
    for (int w = 0; w < 3; ++w)
#pragma unroll
        for (int j = 0; j < 4; ++j) {
            const f2 o = dpp_quad<DPP_XOR2>(v[w][j]);
            v[w][j] = ab2(A2, v[w][j], B2, o);
        }
    // h=4 (shfl)
#pragma unroll
    for (int w = 0; w < 3; ++w)
#pragma unroll
        for (int j = 0; j < 4; ++j) {
            const f2 o = shfl_xor_c(v[w][j], 4);
            v[w][j] = ab2(A4, v[w][j], B4, o);
        }
    // h=8 (shfl)
#pragma unroll
    for (int w = 0; w < 3; ++w)
#pragma unroll
        for (int j = 0; j < 4; ++j) {
            const f2 o = shfl_xor_c(v[w][j], 8);
            v[w][j] = ab2(A8, v[w][j], B8, o);
        }
    // h=16 (swap): v' = a + S16*b
#pragma unroll
    for (int w = 0; w < 3; ++w)
#pragma unroll
        for (int j = 0; j < 4; ++j) {
#if USE_PL16
            f2 a, bb; swap16c(v[w][j], a, bb);
            v[w][j] = cfma2(S16, bb, a);
#else
            const f2 o = shfl_xor_c(v[w][j], 16);
            v[w][j] = ab2(A16, v[w][j], B16, o);
#endif
        }
    // h=32 (swap): v' = a + S32*b
#pragma unroll
    for (int w = 0; w < 3; ++w)
#pragma unroll
        for (int j = 0; j < 4; ++j) {
#if USE_PL32
            f2 a, bb; swap32c(v[w][j], a, bb);
            v[w][j] = cfma2(S32, bb, a);
#else
            const f2 o = shfl_xor_c(v[w][j], 32);
            v[w][j] = ab2(A32, v[w][j], B32, o);
#endif
        }
    // in-register h=64, h=128
#pragma unroll
    for (int w = 0; w < 3; ++w) {
        f2 tv = cmul(w64, v[w][1]);
        f2 a = v[w][0];
        v[w][0] = a + tv; v[w][1] = a - tv;
        tv = cmul(w64, v[w][3]);
        a = v[w][2];
        v[w][2] = a + tv; v[w][3] = a - tv;
        tv = cmul(wi0, v[w][2]);
        a = v[w][0];
        v[w][0] = a + tv; v[w][2] = a - tv;
        tv = cmul(wi1, v[w][3]);
        a = v[w][1];
        v[w][1] = a + tv; v[w][3] = a - tv;
    }

    float acc = 0.0f;
#pragma unroll
    for (int w = 0; w < 3; ++w)
#pragma unroll
        for (int j = 0; j < 4; ++j) {
            const f2 sq = v[w][j] * v[w][j];
            acc += __builtin_amdgcn_sqrtf(sq[0] + sq[1]);
        }

#pragma unroll
    for (int off = 32; off > 0; off >>= 1) acc += __shfl_xor(acc, off, 64);

    if (lane == 0) {
        const float focused = acc * (1.0f / (256.0f * 256.0f * 3.0f));
        out[b * 512 + m] = (focused > 0.3f) ? focused : 0.0f;
    }
}

extern "C" void kernel_launch(void* const* d_in, const int* in_sizes, int n_in,
                              void* d_out, int out_size, void* d_ws, size_t ws_size,
                              hipStream_t stream) {
    (void)in_sizes; (void)n_in; (void)out_size; (void)ws_size;
    const float* stim = (const float*)d_in[0];   // (32, 32768)
    const float* Hr   = (const float*)d_in[1];   // (512, 256, 3)
    const float* Hi   = (const float*)d_in[2];   // (512, 256, 3)
    float* out = (float*)d_out;                  // (32, 512)

    h2v* yh  = (h2v*)d_ws;                                                 // 4 MB (fp16)
    h2v* Hth = (h2v*)((char*)d_ws + (size_t)32 * 128 * 256 * sizeof(h2v)); // 1.5 MB (fp16)

    k_cols<<<256 + 512, 256, 0, stream>>>(stim, yh, Hr, Hi, Hth);
    k_recon<<<4096, 256, 0, stream>>>(yh, Hth, out);
}